// Round 1
// baseline (484.748 us; speedup 1.0000x reference)
//
#include <hip/hip_runtime.h>
#include <math.h>

#define NW 4  // waves (matrices) per block

__device__ __forceinline__ void wave_sync() {
  // Wave-internal LDS sync: wait for all outstanding LDS ops, and fence the
  // compiler so it cannot hoist later ds_reads above earlier ds_writes.
  asm volatile("s_waitcnt lgkmcnt(0)" ::: "memory");
  __builtin_amdgcn_wave_barrier();
}

// C[r4..r4+3][c4..c4+3] += sum_k X[k][r4+i] * Y[k][c4+j]  ( = (X^T Y) tile;
// X symmetric => X^T Y = X*Y ). Both operands read row-wise: broadcast b128.
__device__ __forceinline__ void mm_acc(const float* __restrict__ X,
                                       const float* __restrict__ Y,
                                       int r4, int c4, float acc[4][4]) {
#pragma unroll 8
  for (int k = 0; k < 32; ++k) {
    float4 xv = *(const float4*)(X + k * 32 + r4);
    float4 yv = *(const float4*)(Y + k * 32 + c4);
    float xs[4] = {xv.x, xv.y, xv.z, xv.w};
    float ys[4] = {yv.x, yv.y, yv.z, yv.w};
#pragma unroll
    for (int i = 0; i < 4; ++i)
#pragma unroll
      for (int j = 0; j < 4; ++j)
        acc[i][j] = fmaf(xs[i], ys[j], acc[i][j]);
  }
}

__global__ __launch_bounds__(256) void expm32_kernel(const float* __restrict__ in,
                                                     float* __restrict__ out,
                                                     int nmat) {
  __shared__ float smem[NW][2][1024];
  const int lane = threadIdx.x & 63;
  const int wid = threadIdx.x >> 6;
  const int m = blockIdx.x * NW + wid;
  if (m >= nmat) return;

  float* bufP = smem[wid][0];  // scaled A first, later the running P
  float* buf2 = smem[wid][1];  // A^2
  const float* src = in + (size_t)m * 1024;
  float* dst = out + (size_t)m * 1024;

  const int r4 = (lane >> 3) << 2;  // row base of this lane's 4x4 tile
  const int c4 = (lane & 7) << 2;   // col base

  // ---- load (coalesced float4) + Frobenius norm ----
  float4 v0 = *(const float4*)(src + 0 * 256 + lane * 4);
  float4 v1 = *(const float4*)(src + 1 * 256 + lane * 4);
  float4 v2 = *(const float4*)(src + 2 * 256 + lane * 4);
  float4 v3 = *(const float4*)(src + 3 * 256 + lane * 4);
  float ss = v0.x * v0.x + v0.y * v0.y + v0.z * v0.z + v0.w * v0.w +
             v1.x * v1.x + v1.y * v1.y + v1.z * v1.z + v1.w * v1.w +
             v2.x * v2.x + v2.y * v2.y + v2.z * v2.z + v2.w * v2.w +
             v3.x * v3.x + v3.y * v3.y + v3.z * v3.z + v3.w * v3.w;
#pragma unroll
  for (int o = 32; o > 0; o >>= 1) ss += __shfl_xor(ss, o, 64);
  float F = sqrtf(ss);

  // s such that ||A/2^s||_F <= 1 (=> spectral norm <= 1)
  int s = 0;
  if (F > 1.0f) {
    int e;
    frexpf(F, &e);  // F = mant * 2^e, mant in [0.5,1)
    s = e;
    if (s > 30) s = 30;
  }
  const float sc = __int_as_float((127 - s) << 23);  // exact 2^-s

  // scaled A -> bufP (row-major, stride 32)
  {
    float4 w;
    w.x = v0.x * sc; w.y = v0.y * sc; w.z = v0.z * sc; w.w = v0.w * sc;
    *(float4*)(bufP + 0 * 256 + lane * 4) = w;
    w.x = v1.x * sc; w.y = v1.y * sc; w.z = v1.z * sc; w.w = v1.w * sc;
    *(float4*)(bufP + 1 * 256 + lane * 4) = w;
    w.x = v2.x * sc; w.y = v2.y * sc; w.z = v2.z * sc; w.w = v2.w * sc;
    *(float4*)(bufP + 2 * 256 + lane * 4) = w;
    w.x = v3.x * sc; w.y = v3.y * sc; w.z = v3.z * sc; w.w = v3.w * sc;
    *(float4*)(bufP + 3 * 256 + lane * 4) = w;
  }
  wave_sync();

  // lane's 4x4 tile of scaled A (for the cI + cA*A group terms)
  float At[4][4];
#pragma unroll
  for (int i = 0; i < 4; ++i) {
    float4 t = *(const float4*)(bufP + (r4 + i) * 32 + c4);
    At[i][0] = t.x; At[i][1] = t.y; At[i][2] = t.z; At[i][3] = t.w;
  }

  // ---- A2 = A*A ----
  float A2t[4][4] = {{0.f}};
  mm_acc(bufP, bufP, r4, c4, A2t);
#pragma unroll
  for (int i = 0; i < 4; ++i) {
    float4 t;
    t.x = A2t[i][0]; t.y = A2t[i][1]; t.z = A2t[i][2]; t.w = A2t[i][3];
    *(float4*)(buf2 + (r4 + i) * 32 + c4) = t;
  }

  // ---- Taylor degree 8, Paterson-Stockmeyer in y = A2 ----
  // P3 = c6 I + c7 A + c8 A2 ; then 3 Horner steps: P <- P*A2 + (cI*I + cA*A)
  const float c6f = 1.f / 720.f, c7f = 1.f / 5040.f, c8f = 1.f / 40320.f;
  float P[4][4];
#pragma unroll
  for (int i = 0; i < 4; ++i)
#pragma unroll
    for (int j = 0; j < 4; ++j) {
      float p = c7f * At[i][j] + c8f * A2t[i][j];
      if (r4 + i == c4 + j) p += c6f;
      P[i][j] = p;
    }
  // write P over bufP (reads of old A finished in-order within the wave)
#pragma unroll
  for (int i = 0; i < 4; ++i) {
    float4 t;
    t.x = P[i][0]; t.y = P[i][1]; t.z = P[i][2]; t.w = P[i][3];
    *(float4*)(bufP + (r4 + i) * 32 + c4) = t;
  }
  wave_sync();

  const float cIs[3] = {1.f / 24.f, 0.5f, 1.f};
  const float cAs[3] = {1.f / 120.f, 1.f / 6.f, 1.f};
#pragma unroll
  for (int st = 0; st < 3; ++st) {
    float N[4][4];
#pragma unroll
    for (int i = 0; i < 4; ++i)
#pragma unroll
      for (int j = 0; j < 4; ++j) {
        float p = cAs[st] * At[i][j];
        if (r4 + i == c4 + j) p += cIs[st];
        N[i][j] = p;
      }
    mm_acc(bufP, buf2, r4, c4, N);
#pragma unroll
    for (int i = 0; i < 4; ++i) {
#pragma unroll
      for (int j = 0; j < 4; ++j) P[i][j] = N[i][j];
      float4 t;
      t.x = P[i][0]; t.y = P[i][1]; t.z = P[i][2]; t.w = P[i][3];
      *(float4*)(bufP + (r4 + i) * 32 + c4) = t;
    }
    wave_sync();
  }

  // ---- s squarings (P in bufP already) ----
  for (int q = 0; q < s; ++q) {
    float N[4][4] = {{0.f}};
    mm_acc(bufP, bufP, r4, c4, N);
#pragma unroll
    for (int i = 0; i < 4; ++i) {
#pragma unroll
      for (int j = 0; j < 4; ++j) P[i][j] = N[i][j];
      float4 t;
      t.x = P[i][0]; t.y = P[i][1]; t.z = P[i][2]; t.w = P[i][3];
      *(float4*)(bufP + (r4 + i) * 32 + c4) = t;
    }
    wave_sync();
  }

  // ---- store ----
#pragma unroll
  for (int i = 0; i < 4; ++i) {
    float4 t;
    t.x = P[i][0]; t.y = P[i][1]; t.z = P[i][2]; t.w = P[i][3];
    *(float4*)(dst + (size_t)(r4 + i) * 32 + c4) = t;
  }
}

extern "C" void kernel_launch(void* const* d_in, const int* in_sizes, int n_in,
                              void* d_out, int out_size, void* d_ws, size_t ws_size,
                              hipStream_t stream) {
  const float* in = (const float*)d_in[0];
  float* out = (float*)d_out;
  const int nmat = in_sizes[0] >> 10;  // 65536 matrices of 32*32
  const int blocks = (nmat + NW - 1) / NW;
  expm32_kernel<<<blocks, 256, 0, stream>>>(in, out, nmat);
}

// Round 2
// 194.273 us; speedup vs baseline: 2.4952x; 2.4952x over previous
//
#include <hip/hip_runtime.h>
#include <math.h>

#define NW 4  // waves (matrices) per block

typedef __attribute__((ext_vector_type(4))) float f32x4;
typedef __attribute__((ext_vector_type(8))) short s16x8;

__device__ __forceinline__ void wave_sync() {
  asm volatile("s_waitcnt lgkmcnt(0)" ::: "memory");
  __builtin_amdgcn_wave_barrier();
}

__device__ __forceinline__ f32x4 mfma16(s16x8 a, s16x8 b, f32x4 c) {
  return __builtin_amdgcn_mfma_f32_16x16x32_bf16(a, b, c, 0, 0, 0);
}

// Swizzled element index into a [32][32] ushort buffer.
// XOR by (row&3)<<3 spreads banks; preserves 4- and 8-element contiguity.
__device__ __forceinline__ int swz(int row, int k) {
  return row * 32 + (k ^ ((row & 3) << 3));
}

// A/B fragment for 16x16x32 bf16: lane holds row (16*t + rr), k = 8*p .. 8*p+7
// (contiguous). Symmetric operands => same data serves A- and B-roles.
__device__ __forceinline__ s16x8 frag_load(const ushort* buf, int t, int rr, int p) {
  int row = 16 * t + rr;
  int kb = (8 * p) ^ ((row & 3) << 3);
  return *(const s16x8*)(buf + row * 32 + kb);
}

// fp32 -> (hi bf16, lo bf16) by truncation; lo = exact residual truncated.
__device__ __forceinline__ void pack_pair(const f32x4 v, ushort4* hv, ushort4* lv) {
  uint u0 = __float_as_uint(v.x), u1 = __float_as_uint(v.y),
       u2 = __float_as_uint(v.z), u3 = __float_as_uint(v.w);
  float l0 = v.x - __uint_as_float(u0 & 0xffff0000u);
  float l1 = v.y - __uint_as_float(u1 & 0xffff0000u);
  float l2 = v.z - __uint_as_float(u2 & 0xffff0000u);
  float l3 = v.w - __uint_as_float(u3 & 0xffff0000u);
  hv->x = (ushort)(u0 >> 16); hv->y = (ushort)(u1 >> 16);
  hv->z = (ushort)(u2 >> 16); hv->w = (ushort)(u3 >> 16);
  lv->x = (ushort)(__float_as_uint(l0) >> 16);
  lv->y = (ushort)(__float_as_uint(l1) >> 16);
  lv->z = (ushort)(__float_as_uint(l2) >> 16);
  lv->w = (ushort)(__float_as_uint(l3) >> 16);
}

__global__ __launch_bounds__(256) void expm32_kernel(const float* __restrict__ in,
                                                     float* __restrict__ out, int nmat) {
  __shared__ ushort smem[NW][4][1024];  // Ph, Pl, Bh, Bl per wave; 32 KB total
  const int lane = threadIdx.x & 63;
  const int wid = threadIdx.x >> 6;
  const int m = blockIdx.x * NW + wid;
  if (m >= nmat) return;

  ushort* bPh = smem[wid][0];
  ushort* bPl = smem[wid][1];
  ushort* bBh = smem[wid][2];
  ushort* bBl = smem[wid][3];

  const float* src = in + (size_t)m * 1024;
  float* dst = out + (size_t)m * 1024;

  const int q = lane >> 4;  // 0..3: C-layout row group & frag k-group
  const int c = lane & 15;  // 0..15: C-layout col & frag row

  // ---- load (coalesced float4) + Frobenius norm ----
  float4 v[4];
#pragma unroll
  for (int b = 0; b < 4; ++b) v[b] = *(const float4*)(src + b * 256 + lane * 4);
  float ss = 0.f;
#pragma unroll
  for (int b = 0; b < 4; ++b)
    ss += v[b].x * v[b].x + v[b].y * v[b].y + v[b].z * v[b].z + v[b].w * v[b].w;
#pragma unroll
  for (int o = 32; o > 0; o >>= 1) ss += __shfl_xor(ss, o, 64);
  float F = sqrtf(ss);

  // smallest s with F / 2^s <= 1.5
  int s = 0;
  {
    float t = F * 0.6666667f;
    if (t > 1.f) {
      uint bt = __float_as_uint(t);
      s = (int)((bt >> 23) & 0xff) - 127 + (((bt & 0x7fffffu) != 0u) ? 1 : 0);
      if (s < 0) s = 0;
      if (s > 30) s = 30;
    }
  }
  const float sc = __uint_as_float((uint)(127 - s) << 23);  // exact 2^-s

  // ---- pack scaled A (hi/lo bf16) into bufP ----
#pragma unroll
  for (int b = 0; b < 4; ++b) {
    int row = b * 8 + (lane >> 3);
    int colb = (lane & 7) * 4;
    int ph = swz(row, colb);
    f32x4 w;
    w.x = v[b].x * sc; w.y = v[b].y * sc; w.z = v[b].z * sc; w.w = v[b].w * sc;
    ushort4 hv, lv;
    pack_pair(w, &hv, &lv);
    *(ushort4*)(bPh + ph) = hv;
    *(ushort4*)(bPl + ph) = lv;
  }
  wave_sync();

  // ---- A fragments + A values at C-layout (for linear terms) ----
  s16x8 Ah[2], Al[2];
#pragma unroll
  for (int tt = 0; tt < 2; ++tt) {
    Ah[tt] = frag_load(bPh, tt, c, q);
    Al[tt] = frag_load(bPl, tt, c, q);
  }
  float dmask[4];
#pragma unroll
  for (int r = 0; r < 4; ++r) dmask[r] = (c == 4 * q + r) ? 1.f : 0.f;
  f32x4 Af[2][2];
#pragma unroll
  for (int ti = 0; ti < 2; ++ti)
#pragma unroll
    for (int tj = 0; tj < 2; ++tj) {
      f32x4 a;
#pragma unroll
      for (int r = 0; r < 4; ++r) {
        int ph = swz(16 * ti + 4 * q + r, 16 * tj + c);
        a[r] = __uint_as_float(((uint)bPh[ph]) << 16) +
               __uint_as_float(((uint)bPl[ph]) << 16);
      }
      Af[ti][tj] = a;
    }

  // ---- A2 = A*A (split-precision MFMA) ----
  f32x4 acc[2][2];
#pragma unroll
  for (int ti = 0; ti < 2; ++ti)
#pragma unroll
    for (int tj = 0; tj < 2; ++tj) {
      f32x4 z = {0.f, 0.f, 0.f, 0.f};
      z = mfma16(Ah[ti], Ah[tj], z);
      z = mfma16(Ah[ti], Al[tj], z);
      z = mfma16(Al[ti], Ah[tj], z);
      acc[ti][tj] = z;
    }

  // ---- pack A2 -> bufB; P3 = c6 I + c7 A + c8 A2 -> bufP (transpose-store) ----
  const float c6f = 1.f / 720.f, c7f = 1.f / 5040.f, c8f = 1.f / 40320.f;
#pragma unroll
  for (int ti = 0; ti < 2; ++ti)
#pragma unroll
    for (int tj = 0; tj < 2; ++tj) {
      int ph = swz(16 * tj + c, 16 * ti + 4 * q);
      ushort4 hv, lv;
      pack_pair(acc[ti][tj], &hv, &lv);
      *(ushort4*)(bBh + ph) = hv;
      *(ushort4*)(bBl + ph) = lv;
      f32x4 p3;
#pragma unroll
      for (int r = 0; r < 4; ++r) {
        float d = (ti == tj) ? c6f * dmask[r] : 0.f;
        p3[r] = c8f * acc[ti][tj][r] + c7f * Af[ti][tj][r] + d;
      }
      pack_pair(p3, &hv, &lv);
      *(ushort4*)(bPh + ph) = hv;
      *(ushort4*)(bPl + ph) = lv;
    }
  wave_sync();

  // ---- A2 fragments (reused across all 3 Horner steps) ----
  s16x8 Bh[2], Bl[2];
#pragma unroll
  for (int tt = 0; tt < 2; ++tt) {
    Bh[tt] = frag_load(bBh, tt, c, q);
    Bl[tt] = frag_load(bBl, tt, c, q);
  }

  // ---- 3 Horner steps: P <- P*A2 + (cI*I + cA*A) ----
  const float cIs[3] = {1.f / 24.f, 0.5f, 1.f};
  const float cAs[3] = {1.f / 120.f, 1.f / 6.f, 1.f};
#pragma unroll
  for (int st = 0; st < 3; ++st) {
    s16x8 Ph[2], Pl[2];
#pragma unroll
    for (int tt = 0; tt < 2; ++tt) {
      Ph[tt] = frag_load(bPh, tt, c, q);
      Pl[tt] = frag_load(bPl, tt, c, q);
    }
#pragma unroll
    for (int ti = 0; ti < 2; ++ti)
#pragma unroll
      for (int tj = 0; tj < 2; ++tj) {
        f32x4 z;
#pragma unroll
        for (int r = 0; r < 4; ++r) {
          float d = (ti == tj) ? cIs[st] * dmask[r] : 0.f;
          z[r] = cAs[st] * Af[ti][tj][r] + d;
        }
        z = mfma16(Ph[ti], Bh[tj], z);
        z = mfma16(Ph[ti], Bl[tj], z);
        z = mfma16(Pl[ti], Bh[tj], z);
        acc[ti][tj] = z;
      }
#pragma unroll
    for (int ti = 0; ti < 2; ++ti)
#pragma unroll
      for (int tj = 0; tj < 2; ++tj) {
        int ph = swz(16 * tj + c, 16 * ti + 4 * q);
        ushort4 hv, lv;
        pack_pair(acc[ti][tj], &hv, &lv);
        *(ushort4*)(bPh + ph) = hv;
        *(ushort4*)(bPl + ph) = lv;
      }
    wave_sync();
  }

  // ---- s squarings ----
  for (int sq = 0; sq < s; ++sq) {
    s16x8 Ph[2], Pl[2];
#pragma unroll
    for (int tt = 0; tt < 2; ++tt) {
      Ph[tt] = frag_load(bPh, tt, c, q);
      Pl[tt] = frag_load(bPl, tt, c, q);
    }
#pragma unroll
    for (int ti = 0; ti < 2; ++ti)
#pragma unroll
      for (int tj = 0; tj < 2; ++tj) {
        f32x4 z = {0.f, 0.f, 0.f, 0.f};
        z = mfma16(Ph[ti], Ph[tj], z);
        z = mfma16(Ph[ti], Pl[tj], z);
        z = mfma16(Pl[ti], Ph[tj], z);
        acc[ti][tj] = z;
      }
    if (sq + 1 < s) {
#pragma unroll
      for (int ti = 0; ti < 2; ++ti)
#pragma unroll
        for (int tj = 0; tj < 2; ++tj) {
          int ph = swz(16 * tj + c, 16 * ti + 4 * q);
          ushort4 hv, lv;
          pack_pair(acc[ti][tj], &hv, &lv);
          *(ushort4*)(bPh + ph) = hv;
          *(ushort4*)(bPl + ph) = lv;
        }
      wave_sync();
    }
  }

  // ---- store (transpose-store; result symmetric) ----
#pragma unroll
  for (int ti = 0; ti < 2; ++ti)
#pragma unroll
    for (int tj = 0; tj < 2; ++tj)
      *(f32x4*)(dst + (size_t)((16 * tj + c) * 32 + 16 * ti + 4 * q)) = acc[ti][tj];
}

extern "C" void kernel_launch(void* const* d_in, const int* in_sizes, int n_in,
                              void* d_out, int out_size, void* d_ws, size_t ws_size,
                              hipStream_t stream) {
  const float* in = (const float*)d_in[0];
  float* out = (float*)d_out;
  const int nmat = in_sizes[0] >> 10;
  const int blocks = (nmat + NW - 1) / NW;
  expm32_kernel<<<blocks, 256, 0, stream>>>(in, out, nmat);
}

// Round 3
// 151.483 us; speedup vs baseline: 3.2000x; 1.2825x over previous
//
#include <hip/hip_runtime.h>
#include <math.h>

#define NW 4  // waves (matrices) per block, no inter-wave interaction

typedef __attribute__((ext_vector_type(16))) float f32x16;
typedef __attribute__((ext_vector_type(8))) short s16x8;
typedef __attribute__((ext_vector_type(4))) unsigned int u32x4;

struct Frag { s16x8 h0, h1, l0, l1; };  // bf16 hi/lo, k-halves 0..15 / 16..31

__device__ __forceinline__ f32x16 mfma32(s16x8 a, s16x8 b, f32x16 c) {
  return __builtin_amdgcn_mfma_f32_32x32x16_bf16(a, b, c, 0, 0, 0);
}

// C += X*Y in split precision: XhYh + XhYl + XlYh  (XlYl ~ 2^-16 rel, dropped)
__device__ __forceinline__ f32x16 matmul(const Frag& X, const Frag& Y, f32x16 acc) {
  acc = mfma32(X.h0, Y.h0, acc);
  acc = mfma32(X.h1, Y.h1, acc);
  acc = mfma32(X.h0, Y.l0, acc);
  acc = mfma32(X.h1, Y.l1, acc);
  acc = mfma32(X.l0, Y.h0, acc);
  acc = mfma32(X.l1, Y.h1, acc);
  return acc;
}

__device__ __forceinline__ s16x8 mk(uint a, uint b, uint c, uint d) {
  union { u32x4 u; s16x8 s; } t;
  t.u = (u32x4){a, b, c, d};
  return t.s;
}

// C/D layout (col=lane&31, row=(reg&3)+8*(reg>>2)+4*hi) -> next A/B fragment
// (row=lane&31, k=16f+8*hi+j, j=0..7 contiguous), via symmetry C^T = C.
// Element j   (j=0..3): hi=0 wants own reg 8f+j;     hi=1 wants partner reg 8f+4+j.
// Element j+4        : hi=0 wants partner reg 8f+j;  hi=1 wants own reg 8f+4+j.
// One permlane32_swap(old=C[8f+4+j], src=C[8f+j]) yields BOTH:
//   r[1] = {l<32: src[l] ; l>=32: old[l-32]} = element j
//   r[0] = {l<32: src[l+32] ; l>=32: old[l]} = element j+4
__device__ __forceinline__ Frag convert(const f32x16 c) {
  uint e[16];
#pragma unroll
  for (int f = 0; f < 2; ++f)
#pragma unroll
    for (int j = 0; j < 4; ++j) {
      auto r = __builtin_amdgcn_permlane32_swap(
          __float_as_uint(c[8 * f + 4 + j]), __float_as_uint(c[8 * f + j]),
          false, false);
      e[8 * f + j] = r[1];
      e[8 * f + 4 + j] = r[0];
    }
  uint hw[8], lw[8];
#pragma unroll
  for (int p = 0; p < 8; ++p) {
    uint u0 = e[2 * p], u1 = e[2 * p + 1];
    uint h0 = u0 & 0xffff0000u, h1 = u1 & 0xffff0000u;
    float l0 = __uint_as_float(u0) - __uint_as_float(h0);
    float l1 = __uint_as_float(u1) - __uint_as_float(h1);
    hw[p] = h1 | (h0 >> 16);
    lw[p] = (__float_as_uint(l1) & 0xffff0000u) | (__float_as_uint(l0) >> 16);
  }
  Frag F;
  F.h0 = mk(hw[0], hw[1], hw[2], hw[3]);
  F.h1 = mk(hw[4], hw[5], hw[6], hw[7]);
  F.l0 = mk(lw[0], lw[1], lw[2], lw[3]);
  F.l1 = mk(lw[4], lw[5], lw[6], lw[7]);
  return F;
}

__global__ __launch_bounds__(256) void expm32_kernel(const float* __restrict__ in,
                                                     float* __restrict__ out, int nmat) {
  const int lane = threadIdx.x & 63;
  const int wid = threadIdx.x >> 6;
  const int m = blockIdx.x * NW + wid;
  if (m >= nmat) return;
  const int c32 = lane & 31, hi = lane >> 5;
  const float* src = in + (size_t)m * 1024;
  float* dst = out + (size_t)m * 1024;

  // Load A directly in C-layout via symmetry: reg 4g+q <- A[c32][8g+4hi+q]
  f32x16 A;
#pragma unroll
  for (int g = 0; g < 4; ++g) {
    float4 v = *(const float4*)(src + c32 * 32 + g * 8 + hi * 4);
    A[4 * g + 0] = v.x; A[4 * g + 1] = v.y; A[4 * g + 2] = v.z; A[4 * g + 3] = v.w;
  }

  // diag mask in C-layout
  float dm[16];
#pragma unroll
  for (int r = 0; r < 16; ++r)
    dm[r] = ((r & 3) + 8 * (r >> 2) + 4 * hi == c32) ? 1.f : 0.f;

  // ||A||_F^2 (each element counted once across the wave)
  float ss = 0.f;
#pragma unroll
  for (int r = 0; r < 16; ++r) ss = fmaf(A[r], A[r], ss);
#pragma unroll
  for (int o = 32; o > 0; o >>= 1) ss += __shfl_xor(ss, o, 64);

  // A2 = A*A (unscaled)
  Frag FA = convert(A);
  f32x16 acc;
#pragma unroll
  for (int r = 0; r < 16; ++r) acc[r] = 0.f;
  acc = matmul(FA, FA, acc);

  // ||A2||_F^2
  float ss2 = 0.f;
#pragma unroll
  for (int r = 0; r < 16; ++r) ss2 = fmaf(acc[r], acc[r], ss2);
#pragma unroll
  for (int o = 32; o > 0; o >>= 1) ss2 += __shfl_xor(ss2, o, 64);

  // lambda_max^2 <= min(||A||_F^2, ||A2||_F); smallest s with bound/2^s <= theta=2
  float t2 = fminf(ss, sqrtf(ss2));
  float v = t2 * 0.25f;  // (bound/theta)^2
  int s = 0;
  if (v > 1.f) {
    uint u = __float_as_uint(v);
    int e = (int)((u >> 23) & 255) - 127;
    if (u & 0x7fffffu) ++e;   // ceil(log2 v)
    s = (e + 1) >> 1;         // ceil(e/2): 4^s >= v
    if (s > 15) s = 15;
  }
  const float sc = __uint_as_float((uint)(127 - s) << 23);  // exact 2^-s
  const float sc2 = sc * sc;

  // scaled A2' and its fragments (B-operand for all Horner steps)
  f32x16 B2;
#pragma unroll
  for (int r = 0; r < 16; ++r) B2[r] = acc[r] * sc2;
  Frag FB = convert(B2);

  // P3 = c6 I + c7 A' + c8 A2'
  const float c6f = 1.f / 720.f, c7s = (1.f / 5040.f) * sc, c8f = 1.f / 40320.f;
  f32x16 R;
#pragma unroll
  for (int r = 0; r < 16; ++r)
    R[r] = fmaf(c8f, B2[r], fmaf(c7s, A[r], c6f * dm[r]));
  Frag FP = convert(R);

  // 3 Horner steps: P <- P*A2' + cI*I + cA*A'   (linear term seeds the MFMA acc)
  const float cIs[3] = {1.f / 24.f, 0.5f, 1.f};
  const float cAs[3] = {1.f / 120.f, 1.f / 6.f, 1.f};
#pragma unroll
  for (int st = 0; st < 3; ++st) {
    const float cA = cAs[st] * sc;
    f32x16 z;
#pragma unroll
    for (int r = 0; r < 16; ++r) z[r] = fmaf(cIs[st], dm[r], cA * A[r]);
    z = matmul(FP, FB, z);
    R = z;
    FP = convert(R);
  }

  // s squarings (wave-uniform trip count; no barriers anywhere)
  for (int i = 0; i < s; ++i) {
    f32x16 z;
#pragma unroll
    for (int r = 0; r < 16; ++r) z[r] = 0.f;
    z = matmul(FP, FP, z);
    R = z;
    if (i + 1 < s) FP = convert(R);
  }

  // store (transpose of C-layout via symmetry; mirrors the load pattern)
#pragma unroll
  for (int g = 0; g < 4; ++g) {
    float4 w;
    w.x = R[4 * g + 0]; w.y = R[4 * g + 1]; w.z = R[4 * g + 2]; w.w = R[4 * g + 3];
    *(float4*)(dst + c32 * 32 + g * 8 + hi * 4) = w;
  }
}

extern "C" void kernel_launch(void* const* d_in, const int* in_sizes, int n_in,
                              void* d_out, int out_size, void* d_ws, size_t ws_size,
                              hipStream_t stream) {
  const float* in = (const float*)d_in[0];
  float* out = (float*)d_out;
  const int nmat = in_sizes[0] >> 10;
  const int blocks = (nmat + NW - 1) / NW;
  expm32_kernel<<<blocks, 256, 0, stream>>>(in, out, nmat);
}

// Round 4
// 130.529 us; speedup vs baseline: 3.7137x; 1.1605x over previous
//
#include <hip/hip_runtime.h>
#include <math.h>

#define NW 4  // waves (matrices) per block, no inter-wave interaction

typedef __attribute__((ext_vector_type(16))) float f32x16;
typedef __attribute__((ext_vector_type(8))) short s16x8;
typedef __attribute__((ext_vector_type(4))) unsigned int u32x4;

struct Frag { s16x8 h0, h1, l0, l1; };  // bf16 hi/lo, k-halves 0..15 / 16..31

__device__ __forceinline__ f32x16 mfma32(s16x8 a, s16x8 b, f32x16 c) {
  return __builtin_amdgcn_mfma_f32_32x32x16_bf16(a, b, c, 0, 0, 0);
}

// C += X*Y in split precision: XhYh + XhYl + XlYh  (XlYl ~ 2^-16 rel, dropped)
__device__ __forceinline__ f32x16 matmul(const Frag& X, const Frag& Y, f32x16 acc) {
  acc = mfma32(X.h0, Y.h0, acc);
  acc = mfma32(X.h1, Y.h1, acc);
  acc = mfma32(X.h0, Y.l0, acc);
  acc = mfma32(X.h1, Y.l1, acc);
  acc = mfma32(X.l0, Y.h0, acc);
  acc = mfma32(X.l1, Y.h1, acc);
  return acc;
}

__device__ __forceinline__ s16x8 mk(uint a, uint b, uint c, uint d) {
  union { u32x4 u; s16x8 s; } t;
  t.u = (u32x4){a, b, c, d};
  return t.s;
}

// C/D layout (col=lane&31, row=(reg&3)+8*(reg>>2)+4*hi) -> A/B fragment
// (row=lane&31, k contiguous) via symmetry; 8 permlane32_swap, both outputs used.
__device__ __forceinline__ Frag convert(const f32x16 c) {
  uint e[16];
#pragma unroll
  for (int f = 0; f < 2; ++f)
#pragma unroll
    for (int j = 0; j < 4; ++j) {
      auto r = __builtin_amdgcn_permlane32_swap(
          __float_as_uint(c[8 * f + 4 + j]), __float_as_uint(c[8 * f + j]),
          false, false);
      e[8 * f + j] = r[1];
      e[8 * f + 4 + j] = r[0];
    }
  uint hw[8], lw[8];
#pragma unroll
  for (int p = 0; p < 8; ++p) {
    uint u0 = e[2 * p], u1 = e[2 * p + 1];
    uint h0 = u0 & 0xffff0000u, h1 = u1 & 0xffff0000u;
    float l0 = __uint_as_float(u0) - __uint_as_float(h0);
    float l1 = __uint_as_float(u1) - __uint_as_float(h1);
    hw[p] = h1 | (h0 >> 16);
    lw[p] = (__float_as_uint(l1) & 0xffff0000u) | (__float_as_uint(l0) >> 16);
  }
  Frag F;
  F.h0 = mk(hw[0], hw[1], hw[2], hw[3]);
  F.h1 = mk(hw[4], hw[5], hw[6], hw[7]);
  F.l0 = mk(lw[0], lw[1], lw[2], lw[3]);
  F.l1 = mk(lw[4], lw[5], lw[6], lw[7]);
  return F;
}

__global__ __launch_bounds__(256, 4) void expm32_kernel(const float* __restrict__ in,
                                                        float* __restrict__ out, int nmat) {
  const int lane = threadIdx.x & 63;
  const int wid = threadIdx.x >> 6;
  const int m = blockIdx.x * NW + wid;
  if (m >= nmat) return;
  const int c32 = lane & 31, hi = lane >> 5;
  const float* src = in + (size_t)m * 1024;
  float* dst = out + (size_t)m * 1024;

  // Load A directly in C-layout via symmetry: reg 4g+q <- A[c32][8g+4hi+q]
  f32x16 A;
#pragma unroll
  for (int g = 0; g < 4; ++g) {
    float4 v = *(const float4*)(src + c32 * 32 + g * 8 + hi * 4);
    A[4 * g + 0] = v.x; A[4 * g + 1] = v.y; A[4 * g + 2] = v.z; A[4 * g + 3] = v.w;
  }

  // diag mask in C-layout (row(r) == col)
  float dm[16];
#pragma unroll
  for (int r = 0; r < 16; ++r)
    dm[r] = ((r & 3) + 8 * (r >> 2) + 4 * hi == c32) ? 1.f : 0.f;

  // ---- powers: A2, A3, A4 (all unscaled, split-precision) ----
  Frag FA = convert(A);
  f32x16 zz;
#pragma unroll
  for (int r = 0; r < 16; ++r) zz[r] = 0.f;
  f32x16 A2 = matmul(FA, FA, zz);
  Frag FA2 = convert(A2);
  f32x16 A3 = matmul(FA2, FA, zz);
  f32x16 A4 = matmul(FA2, FA2, zz);

  // ---- ||A4||_F^2 -> scaling s:  lambda^8 <= ||A4||_F^2 ; need (lam/2^s)<=theta ----
  float ss4 = 0.f;
#pragma unroll
  for (int r = 0; r < 16; ++r) ss4 = fmaf(A4[r], A4[r], ss4);
#pragma unroll
  for (int o = 32; o > 0; o >>= 1) ss4 += __shfl_xor(ss4, o, 64);

  // v8 = ||A4||_F^2 / theta^8, theta = 2.3 ; need 256^s >= v8
  float v8 = ss4 * 0.0012770f;
  int s = 0;
  if (v8 > 1.f) {
    uint u = __float_as_uint(v8);
    int e = (int)((u >> 23) & 255) - 127;
    if (u & 0x7fffffu) ++e;  // ceil(log2 v8)
    s = (e + 7) >> 3;        // ceil(e/8)
    if (s > 15) s = 15;
  }
  const float sc = __uint_as_float((uint)(127 - s) << 23);  // exact 2^-s
  const float sc2 = sc * sc, sc3 = sc2 * sc, sc4 = sc2 * sc2;

  // ---- degree-8 Taylor of exp(sc*A):  P = L + A4' * (G + c8*A4') ----
  // L = I + A' + A'^2/2 + A'^3/6 ;  G = I/24 + A'/120 + A'^2/720 + A'^3/5040
  const float l1 = sc, l2 = sc2 * 0.5f, l3 = sc3 * (1.f / 6.f);
  const float g1 = sc * (1.f / 120.f), g2 = sc2 * (1.f / 720.f),
              g3 = sc3 * (1.f / 5040.f), c8s = sc4 * sc4 * (1.f / 40320.f);
  f32x16 L, Bop, A4s;
#pragma unroll
  for (int r = 0; r < 16; ++r) {
    float a = A[r], a2 = A2[r], a3 = A3[r];
    L[r] = fmaf(l3, a3, fmaf(l2, a2, fmaf(l1, a, dm[r])));
    float g = fmaf(g3, a3, fmaf(g2, a2, fmaf(g1, a, (1.f / 24.f) * dm[r])));
    float a4s = A4[r] * sc4;
    A4s[r] = a4s;
    Bop[r] = fmaf(sc4 * (1.f / 40320.f), a4s, g);
  }
  Frag F4 = convert(A4s);
  Frag FB = convert(Bop);
  f32x16 R = matmul(F4, FB, L);

  // ---- s squarings ----
  Frag FP = convert(R);
  for (int i = 0; i < s; ++i) {
    f32x16 z;
#pragma unroll
    for (int r = 0; r < 16; ++r) z[r] = 0.f;
    z = matmul(FP, FP, z);
    R = z;
    if (i + 1 < s) FP = convert(R);
  }

  // ---- store (transpose of C-layout via symmetry; mirrors load) ----
#pragma unroll
  for (int g = 0; g < 4; ++g) {
    float4 w;
    w.x = R[4 * g + 0]; w.y = R[4 * g + 1]; w.z = R[4 * g + 2]; w.w = R[4 * g + 3];
    *(float4*)(dst + (size_t)(c32 * 32 + g * 8 + hi * 4)) = w;
  }
}

extern "C" void kernel_launch(void* const* d_in, const int* in_sizes, int n_in,
                              void* d_out, int out_size, void* d_ws, size_t ws_size,
                              hipStream_t stream) {
  const float* in = (const float*)d_in[0];
  float* out = (float*)d_out;
  const int nmat = in_sizes[0] >> 10;
  const int blocks = (nmat + NW - 1) / NW;
  expm32_kernel<<<blocks, 256, 0, stream>>>(in, out, nmat);
}

// Round 5
// 127.978 us; speedup vs baseline: 3.7878x; 1.0199x over previous
//
#include <hip/hip_runtime.h>
#include <math.h>

#define NW 4  // waves (matrices) per block, no inter-wave interaction

typedef __attribute__((ext_vector_type(16))) float f32x16;
typedef __attribute__((ext_vector_type(8))) short s16x8;
typedef __attribute__((ext_vector_type(4))) unsigned int u32x4;

struct Frag { s16x8 h0, h1, l0, l1; };  // bf16 hi/lo, k-halves 0..15 / 16..31

__device__ __forceinline__ f32x16 mfma32(s16x8 a, s16x8 b, f32x16 c) {
  return __builtin_amdgcn_mfma_f32_32x32x16_bf16(a, b, c, 0, 0, 0);
}

// C += X*Y in split precision: XhYh + XhYl + XlYh  (XlYl ~ 2^-16 rel, dropped)
__device__ __forceinline__ f32x16 matmul(const Frag& X, const Frag& Y, f32x16 acc) {
  acc = mfma32(X.h0, Y.h0, acc);
  acc = mfma32(X.h1, Y.h1, acc);
  acc = mfma32(X.h0, Y.l0, acc);
  acc = mfma32(X.h1, Y.l1, acc);
  acc = mfma32(X.l0, Y.h0, acc);
  acc = mfma32(X.l1, Y.h1, acc);
  return acc;
}

__device__ __forceinline__ s16x8 mk(uint a, uint b, uint c, uint d) {
  union { u32x4 u; s16x8 s; } t;
  t.u = (u32x4){a, b, c, d};
  return t.s;
}

// C/D layout (col=lane&31, row=(reg&3)+8*(reg>>2)+4*hi) -> A/B fragment
// (row=lane&31, k contiguous) via symmetry; 8 permlane32_swap, both outputs
// used. Pack via v_cvt_pk_bf16_f32 (RNE); lo = exact residual.
__device__ __forceinline__ Frag convert(const f32x16 c) {
  uint e[16];
#pragma unroll
  for (int f = 0; f < 2; ++f)
#pragma unroll
    for (int j = 0; j < 4; ++j) {
      auto r = __builtin_amdgcn_permlane32_swap(
          __float_as_uint(c[8 * f + 4 + j]), __float_as_uint(c[8 * f + j]),
          false, false);
      e[8 * f + j] = r[1];
      e[8 * f + 4 + j] = r[0];
    }
  uint hw[8], lw[8];
#pragma unroll
  for (int p = 0; p < 8; ++p) {
    float x0 = __uint_as_float(e[2 * p]);
    float x1 = __uint_as_float(e[2 * p + 1]);
    uint hp;
    asm("v_cvt_pk_bf16_f32 %0, %1, %2" : "=v"(hp) : "v"(x0), "v"(x1));
    float l0 = x0 - __uint_as_float(hp << 16);
    float l1 = x1 - __uint_as_float(hp & 0xffff0000u);
    uint lp;
    asm("v_cvt_pk_bf16_f32 %0, %1, %2" : "=v"(lp) : "v"(l0), "v"(l1));
    hw[p] = hp;
    lw[p] = lp;
  }
  Frag F;
  F.h0 = mk(hw[0], hw[1], hw[2], hw[3]);
  F.h1 = mk(hw[4], hw[5], hw[6], hw[7]);
  F.l0 = mk(lw[0], lw[1], lw[2], lw[3]);
  F.l1 = mk(lw[4], lw[5], lw[6], lw[7]);
  return F;
}

__global__ __launch_bounds__(256, 6) void expm32_kernel(const float* __restrict__ in,
                                                        float* __restrict__ out, int nmat) {
  const int lane = threadIdx.x & 63;
  const int wid = threadIdx.x >> 6;
  const int m = blockIdx.x * NW + wid;
  if (m >= nmat) return;
  const int c32 = lane & 31, hi = lane >> 5;
  const float* src = in + (size_t)m * 1024;
  float* dst = out + (size_t)m * 1024;

  // Load A directly in C-layout via symmetry: reg 4g+q <- A[c32][8g+4hi+q]
  f32x16 A;
#pragma unroll
  for (int g = 0; g < 4; ++g) {
    float4 v = *(const float4*)(src + c32 * 32 + g * 8 + hi * 4);
    A[4 * g + 0] = v.x; A[4 * g + 1] = v.y; A[4 * g + 2] = v.z; A[4 * g + 3] = v.w;
  }

  // Diagonal lives at exactly one reg per lane (when hi matches):
  // reg rd = (c32&3) + 4*(c32>>3), valid iff hi == (c32>>2)&1.
  const int rd = (c32 & 3) | ((c32 >> 1) & 12);
  const bool dval = (hi == ((c32 >> 2) & 1));

  // ---- A2 = A*A (unscaled, split precision) ----
  Frag FA = convert(A);
  f32x16 z;
#pragma unroll
  for (int r = 0; r < 16; ++r) z[r] = 0.f;
  f32x16 A2 = matmul(FA, FA, z);

  // ---- ||A2||_F^2 -> s:  lambda^4 <= ||A2||_F^2; need (lam/2^s) <= theta=3 ----
  float ss2 = 0.f;
#pragma unroll
  for (int r = 0; r < 16; ++r) ss2 = fmaf(A2[r], A2[r], ss2);
#pragma unroll
  for (int o = 32; o > 0; o >>= 1) ss2 += __shfl_xor(ss2, o, 64);
  float v = ss2 * (1.f / 81.f);  // / theta^4
  int s = 0;
  if (v > 1.f) {
    uint u = __float_as_uint(v);
    int e = (int)((u >> 23) & 255) - 127;
    if (u & 0x7fffffu) ++e;  // ceil(log2 v)
    s = (e + 3) >> 2;        // ceil(e/4): 16^s >= v
    if (s > 15) s = 15;
  }
  const float sc = __uint_as_float((uint)(127 - s) << 23);  // exact 2^-s
  const float sc2 = sc * sc;

  // ---- FB = frag(A2') ; P3 = c6 I + c7 A' + c8 A2' ----
  f32x16 B2;
#pragma unroll
  for (int r = 0; r < 16; ++r) B2[r] = A2[r] * sc2;
  Frag FB = convert(B2);
  const float c7s = (1.f / 5040.f) * sc, c8f = 1.f / 40320.f;
#pragma unroll
  for (int r = 0; r < 16; ++r) {
    float d = (dval && r == rd) ? (1.f / 720.f) : 0.f;
    z[r] = fmaf(c8f, B2[r], fmaf(c7s, A[r], d));
  }
  Frag FP = convert(z);

  // ---- 3 Horner steps: P <- P*A2' + cI*I + cA*A' ----
  const float cIs[3] = {1.f / 24.f, 0.5f, 1.f};
  const float cAs[3] = {1.f / 120.f, 1.f / 6.f, 1.f};
  f32x16 R;
#pragma unroll
  for (int st = 0; st < 3; ++st) {
    const float cA = cAs[st] * sc;
#pragma unroll
    for (int r = 0; r < 16; ++r) {
      float d = (dval && r == rd) ? cIs[st] : 0.f;
      z[r] = fmaf(cA, A[r], d);
    }
    R = matmul(FP, FB, z);
    FP = convert(R);
  }

  // ---- s squarings ----
  for (int i = 0; i < s; ++i) {
#pragma unroll
    for (int r = 0; r < 16; ++r) z[r] = 0.f;
    R = matmul(FP, FP, z);
    if (i + 1 < s) FP = convert(R);
  }

  // ---- store (transpose of C-layout via symmetry; mirrors load) ----
#pragma unroll
  for (int g = 0; g < 4; ++g) {
    float4 w;
    w.x = R[4 * g + 0]; w.y = R[4 * g + 1]; w.z = R[4 * g + 2]; w.w = R[4 * g + 3];
    *(float4*)(dst + (size_t)(c32 * 32 + g * 8 + hi * 4)) = w;
  }
}

extern "C" void kernel_launch(void* const* d_in, const int* in_sizes, int n_in,
                              void* d_out, int out_size, void* d_ws, size_t ws_size,
                              hipStream_t stream) {
  const float* in = (const float*)d_in[0];
  float* out = (float*)d_out;
  const int nmat = in_sizes[0] >> 10;
  const int blocks = (nmat + NW - 1) / NW;
  expm32_kernel<<<blocks, 256, 0, stream>>>(in, out, nmat);
}